// Round 7
// baseline (155.006 us; speedup 1.0000x reference)
//
#include <hip/hip_runtime.h>

// RickerCWT via f16 MFMA GEMM, symmetry-halved K (round 11):
//   out[b,s,t] = sum_{d=0..271} W'[s,d] * z[t,d],
//   z[t,d] = x[t+d] + x[t-d],  W'[s,d] = W[s,271+d],  W'[s,0] halved.
// NEW vs r10: occupancy-first tile. 2x2 frags (acc = 64 VGPR, ~115 total)
// -> 4 waves/SIMD via __launch_bounds__(256,4), 4 co-resident blocks/CU
// (was 2). Theory: residual time is phase NON-OVERLAP (epilogue store burst
// ~5us/block + staging + barriers hidden behind only 1 other block). Same
// per-SIMD MFMA issue capacity (4 waves x 4-MFMA ILP vs 2 x 8), double TLP.
// r9's lesson: never force occupancy onto a fat tile (spill); shrink tile so
// the register file allows it natively.
// - Wave tile 64t x 64s, TT=256/block, grid 16x128 = 2048 blocks.
// - z-frag: forward aligned ds_read_b128 (8-shifted-copy Hankel LDS) +
//   backward aligned ds_read_b128 + 8-elem reversal + v_pk_add_f16.
// - B-frags: fragment-ordered f16 wpk (wconv), direct global reads (L1-hot),
//   one coalesced 1KB segment per wave instruction.
// - LDS: xraw 1.6KB + xsm 12.9KB = 14.5KB; 4 blocks/CU = 58KB, fits.

#define TLEN  4096
#define NSC   64
#define KLEN  543
#define PADL  271
#define BLOCK 256
#define TT    256            // t per block (4 waves x 64t)
#define XSRC  808            // raw staged x elems (101 short8)
#define XLEN  800            // per-copy slots (need 0..797)
#define XREG  808            // copy stride in elems (101*8, odd chunk stride)
#define NKS2  17             // K-steps of 16 over d=0..271
#define WPK_N (NKS2 * 2 * 64 * 8)   // 17408 f16 elems

typedef __attribute__((ext_vector_type(8)))  short     short8;
typedef __attribute__((ext_vector_type(8)))  _Float16  half8;
typedef __attribute__((ext_vector_type(16))) float     float16v;
typedef __attribute__((ext_vector_type(4)))  float     float4v;

__global__ __launch_bounds__(256)
void wconv(const float* __restrict__ W, _Float16* __restrict__ wpk)
{
    int idx  = blockIdx.x * 256 + threadIdx.x;    // 0..17407
    int e    = idx & 7;                           // elem within lane's 16B
    int lane = (idx >> 3) & 63;                   // hw lane order
    int st   = (idx >> 9) & 1;                    // s-frag (0: s<32, 1: s>=32)
    int ks   = idx >> 10;                         // K-step of 16 (0..16)
    int n    = lane & 31;
    int q5   = lane >> 5;
    int s    = 32 * st + n;
    int d    = 16 * ks + 8 * q5 + e;              // 0..271
    float v  = W[(size_t)s * KLEN + PADL + d];    // W'[s,d] = W[s,271+d]
    if (d == 0) v *= 0.5f;                        // absorb z[t,0] = 2*x[t]
    wpk[idx] = (_Float16)v;
}

__global__ __launch_bounds__(BLOCK, 4)
void ricker_mfma2(const float* __restrict__ x,
                  const _Float16* __restrict__ wpk,
                  float* __restrict__ out)
{
    __shared__ __align__(16) _Float16 xraw[XSRC];
    __shared__ __align__(16) _Float16 xsm[8 * XREG];   // 12928 B

    const int tid    = threadIdx.x;
    const int tTile  = blockIdx.x;        // 0..15
    const int b      = blockIdx.y;        // 0..127
    const int tStart = tTile * TT;

    // ---- phase A: raw f16 x tile (halo, zero-padded), coalesced ----
    const float* xrow = x + (size_t)b * TLEN;
    for (int i = tid; i < XSRC; i += BLOCK) {
        int g = tStart - PADL + i;
        float v = (g >= 0 && g < TLEN) ? xrow[g] : 0.0f;
        xraw[i] = (_Float16)v;
    }
    __syncthreads();

    // ---- phase B: 8 shifted copies, vectorized b128 (shift c compile-time) --
    // xsm[c*XREG + p] = xraw[p + c], p in [0, XLEN), c in [0,8).
    {
        const short8* xr8 = (const short8*)xraw;
        short8*       xs8 = (short8*)xsm;
        for (int j = tid; j < 100; j += BLOCK) {      // one predicated pass
            short8 lo = xr8[j];
            short8 hi = xr8[j + 1];
            #pragma unroll
            for (int c = 0; c < 8; ++c) {
                short8 r;
                #pragma unroll
                for (int e = 0; e < 8; ++e)
                    r[e] = (c + e < 8) ? lo[c + e] : hi[c + e - 8];
                xs8[c * 101 + j] = r;                 // == xsm[c*XREG + 8j]
            }
        }
    }
    __syncthreads();

    // ---- wave GEMM: 64t x 64s, mfma_f32_32x32x16_f16, 2x2 frags ----
    const int lane = tid & 63;
    const int wv   = tid >> 6;        // 0..3
    const int n    = lane & 31;       // A row m / B col n / D col (s)
    const int q5   = lane >> 5;       // k-half
    const int wt0  = wv * 64;

    // Forward slab: f[j] = x[t+d0+j] = xraw[tau + 271 + d0 + j],
    //   tau = wt0+32tt+n, d0 = 16ks+8q5.  Start S_f = tau+271+d0:
    //   copy cf = (n+7)&7, in-copy slot = wt0+8q5+(n+271-cf) + 16ks+32tt.
    // Backward slab: r[e] = xraw[tau + 264 - d0 + e]  (rev(r)[j]=x[t-d0-j]):
    //   copy cr = n&7,     in-copy slot = wt0-8q5+264+(n-cr) - 16ks+32tt.
    const int cf = (n + 7) & 7;
    const int cr = n & 7;
    const _Float16* af = &xsm[cf * XREG + wt0 + 8 * q5 + (n + PADL - cf)];
    const _Float16* ar = &xsm[cr * XREG + wt0 - 8 * q5 + 264 + (n - cr)];
    // B-frag: per-(ks,st) 1KB block, lane-ordered -> fully coalesced 16B/lane.
    const _Float16* bbase = wpk + (size_t)lane * 8;

    float16v acc[2][2];
    #pragma unroll
    for (int tt = 0; tt < 2; ++tt)
        #pragma unroll
        for (int st = 0; st < 2; ++st)
            #pragma unroll
            for (int e = 0; e < 16; ++e) acc[tt][st][e] = 0.f;

    #pragma unroll 2
    for (int ks = 0; ks < NKS2; ++ks) {
        const int KF = 16 * ks;
        const int BO = 1024 * ks;                        // (ks*2)*512 elems
        half8 bb0 = *(const half8*)&bbase[BO];           // st=0
        half8 bb1 = *(const half8*)&bbase[BO + 512];     // st=1
        half8 z[2];
        #pragma unroll
        for (int tt = 0; tt < 2; ++tt) {
            half8 f = *(const half8*)&af[KF + 32 * tt];
            half8 r = *(const half8*)&ar[32 * tt - KF];
            half8 rv = __builtin_shufflevector(r, r, 7, 6, 5, 4, 3, 2, 1, 0);
            z[tt] = f + rv;                              // v_pk_add_f16 x4
        }
        #pragma unroll
        for (int tt = 0; tt < 2; ++tt) {
            acc[tt][0] = __builtin_amdgcn_mfma_f32_32x32x16_f16(z[tt], bb0, acc[tt][0], 0, 0, 0);
            acc[tt][1] = __builtin_amdgcn_mfma_f32_32x32x16_f16(z[tt], bb1, acc[tt][1], 0, 0, 0);
        }
    }

    // ---- epilogue: D col = n (s), row = (reg&3) + 8*(reg>>2) + 4*q5 (t) ----
    const int tb = tStart + wt0 + 4 * q5;
    float* obase = out + (size_t)b * NSC * TLEN;
    #pragma unroll
    for (int st = 0; st < 2; ++st) {
        #pragma unroll
        for (int tt = 0; tt < 2; ++tt) {
            float16v A = acc[tt][st];
            float* o = obase + (size_t)(32 * st + n) * TLEN + tb + 32 * tt;
            #pragma unroll
            for (int r4 = 0; r4 < 4; ++r4) {
                *(float4v*)&o[8 * r4] =
                    (float4v){A[4 * r4], A[4 * r4 + 1], A[4 * r4 + 2], A[4 * r4 + 3]};
            }
        }
    }
}

extern "C" void kernel_launch(void* const* d_in, const int* in_sizes, int n_in,
                              void* d_out, int out_size, void* d_ws, size_t ws_size,
                              hipStream_t stream) {
    const float* x   = (const float*)d_in[0];   // [128, 4096] fp32
    const float* W   = (const float*)d_in[1];   // [64, 543]  fp32
    float*       out = (float*)d_out;           // [128, 64, 4096] fp32
    _Float16*    wpk = (_Float16*)d_ws;         // [17,2,64,8] f16 blocks (34,816 B)

    wconv<<<dim3(WPK_N / 256), dim3(256), 0, stream>>>(W, wpk);
    dim3 grid(TLEN / TT, 128);                  // (16, 128) = 2048 blocks
    ricker_mfma2<<<grid, dim3(BLOCK), 0, stream>>>(x, wpk, out);
}